// Round 11
// baseline (210.233 us; speedup 1.0000x reference)
//
#include <hip/hip_runtime.h>
#include <hip/hip_bf16.h>
#include <cstddef>
#include <cstdint>

// Problem constants (fixed by the reference setup)
#define N_B   8
#define L_L   4096
#define S_S   4096
#define H_H   8
#define D_D   64
#define NH    64          // N_B * H_H
// KV_aug layout (d-major): rows 0..63 = KV[d][v] (stride 68, cols 64..67 pad),
// row 64 = K_sum[d] (indexed by d in cols 0..63). KVSZ floats per (n,h).
#define KVLD  68
#define KVSZ  (65 * KVLD)   // 4420

typedef const float __attribute__((address_space(1)))* gas_fp;
typedef float __attribute__((address_space(3)))* las_fp;

__device__ __forceinline__ float elu1(float x) {
    // elu(x)+1 : x>0 ? x+1 : exp(x)
    return x > 0.f ? x + 1.f : __expf(x);
}

// ---------------------------------------------------------------------------
// Phase 1 (v6): all-DMA, double-buffered, counted-vmcnt, wave-private.
//  v5 post-mortem: spill fixed, but (a) the wave-private K ds_write map was a
//  32-way bank conflict (SQ_LDS_BANK_CONFLICT 12.8M ~= 20us) and (b) no
//  cross-tile pipelining (vmcnt(0) right after issuing -> full latency/tile).
//  v6: K and V both staged RAW via global_load_lds (linear HW write: zero
//  conflicts, zero held regs -> no spill risk), double-buffered; issue tile
//  t+1's 4 DMAs then s_waitcnt vmcnt(4) (tile t arrived, t+1 in flight).
//  K's elu moves to read time on the fragments (same per-lane elu count as
//  staging-time). Wave w owns s-rows w*8..w*8+7 of each 32-row tile: all LDS
//  traffic wave-private -> zero barriers in the loop.
// ---------------------------------------------------------------------------
__global__ __launch_bounds__(256, 3)
void la_phase1(const float* __restrict__ Kin, const float* __restrict__ Vin,
               float* __restrict__ partials, int split, int schunk)
{
    __shared__ union {
        struct { float K[2][32 * 64]; float V[2][32 * 64]; } st; // 32 KB
        float acc[64 * 68];                                      // 17.3 KB
    } sm;
    __shared__ float sKsumP[4 * 64];     // per-wave ksum partials

    const int b     = blockIdx.x;
    const int nh    = b / split;
    const int chunk = b - nh * split;
    const int n     = nh >> 3;
    const int h     = nh & 7;
    const int s0    = chunk * schunk;

    const int tid  = threadIdx.x;
    const int w    = tid >> 6;
    const int lane = tid & 63;
    const int dg   = lane >> 3;   // d-group: d = dg*8 + i
    const int vg   = lane & 7;    // v-group: v = vg*8 + j

    float acc[8][8];
    #pragma unroll
    for (int i = 0; i < 8; ++i)
        #pragma unroll
        for (int j = 0; j < 8; ++j) acc[i][j] = 0.f;
    float ksum = 0.f;

    const int kd = lane;               // ksum d index (per-wave full coverage)

    // DMA map: wave w stages its own rows w*8..w*8+7 per 32-row tile, in 2
    // chunks of 4 rows (1024B each). lane l -> row chunkbase + (l>>4),
    // col (l&15)*4 (16B); LDS dest linear at float idx (w*8+c*4)*64 + l*4.
    const int drow = lane >> 4;        // 0..3
    const int dcol = (lane & 15) * 4;

    const float* Kb = Kin + (size_t)n * S_S * (H_H * D_D) + h * D_D;
    const float* Vb = Vin + (size_t)n * S_S * (H_H * D_D) + h * D_D;

    const int ntiles = schunk >> 5;    // tiles of 32 s-rows

    // ---- prologue: issue tile 0 into buf 0 (4 DMAs, zero regs held) ----
    #pragma unroll
    for (int c = 0; c < 2; ++c) {
        const int r = w * 8 + c * 4 + drow;
        __builtin_amdgcn_global_load_lds(
            (gas_fp)(Kb + (size_t)(s0 + r) * (H_H * D_D) + dcol),
            (las_fp)&sm.st.K[0][(w * 8 + c * 4) * 64], 16, 0, 0);
        __builtin_amdgcn_global_load_lds(
            (gas_fp)(Vb + (size_t)(s0 + r) * (H_H * D_D) + dcol),
            (las_fp)&sm.st.V[0][(w * 8 + c * 4) * 64], 16, 0, 0);
    }

    for (int t = 0; t < ntiles; ++t) {
        const int buf = t & 1;

        // ---- issue tile t+1 into the other buffer, then counted wait ----
        if (t + 1 < ntiles) {
            const int srow = s0 + (t + 1) * 32;
            #pragma unroll
            for (int c = 0; c < 2; ++c) {
                const int r = w * 8 + c * 4 + drow;
                __builtin_amdgcn_global_load_lds(
                    (gas_fp)(Kb + (size_t)(srow + r) * (H_H * D_D) + dcol),
                    (las_fp)&sm.st.K[buf ^ 1][(w * 8 + c * 4) * 64], 16, 0, 0);
                __builtin_amdgcn_global_load_lds(
                    (gas_fp)(Vb + (size_t)(srow + r) * (H_H * D_D) + dcol),
                    (las_fp)&sm.st.V[buf ^ 1][(w * 8 + c * 4) * 64], 16, 0, 0);
            }
            // tile t's 4 DMAs done; t+1's 4 remain in flight
            asm volatile("s_waitcnt vmcnt(4)" ::: "memory");
        } else {
            asm volatile("s_waitcnt vmcnt(0)" ::: "memory");
        }

        const float* Kbuf = sm.st.K[buf];
        const float* Vbuf = sm.st.V[buf];

        // ---- compute: wave w owns s-rows w*8 .. w*8+7 (raw K, elu at read) ----
        #pragma unroll
        for (int sl = 0; sl < 8; ++sl) {
            const int s = w * 8 + sl;
            const float4 k0 = *(const float4*)&Kbuf[s * 64 + dg * 8];
            const float4 k1 = *(const float4*)&Kbuf[s * 64 + dg * 8 + 4];
            const float4 v0 = *(const float4*)&Vbuf[s * 64 + vg * 8];
            const float4 v1 = *(const float4*)&Vbuf[s * 64 + vg * 8 + 4];
            const float kf[8] = {elu1(k0.x), elu1(k0.y), elu1(k0.z), elu1(k0.w),
                                 elu1(k1.x), elu1(k1.y), elu1(k1.z), elu1(k1.w)};
            const float vf[8] = {v0.x, v0.y, v0.z, v0.w, v1.x, v1.y, v1.z, v1.w};
            #pragma unroll
            for (int i = 0; i < 8; ++i)
                #pragma unroll
                for (int j = 0; j < 8; ++j)
                    acc[i][j] = fmaf(kf[i], vf[j], acc[i][j]);
            // K_sum partial: this wave's own rows, elu applied per element
            ksum += elu1(Kbuf[s * 64 + kd]);
        }
    }
    __syncthreads();   // first block-wide sync: loop done; sm.acc (union) safe

    // cross-wave reduce of acc into sm.acc[d][v] (stride 68), sequential & exact
    for (int ww = 0; ww < 4; ++ww) {
        if (w == ww) {
            #pragma unroll
            for (int i = 0; i < 8; ++i) {
                float* p = &sm.acc[(dg * 8 + i) * 68 + vg * 8];
                if (ww == 0) {
                    *(float4*)p       = make_float4(acc[i][0], acc[i][1], acc[i][2], acc[i][3]);
                    *(float4*)(p + 4) = make_float4(acc[i][4], acc[i][5], acc[i][6], acc[i][7]);
                } else {
                    float4 a0 = *(const float4*)p;
                    float4 a1 = *(const float4*)(p + 4);
                    a0.x += acc[i][0]; a0.y += acc[i][1]; a0.z += acc[i][2]; a0.w += acc[i][3];
                    a1.x += acc[i][4]; a1.y += acc[i][5]; a1.z += acc[i][6]; a1.w += acc[i][7];
                    *(float4*)p       = a0;
                    *(float4*)(p + 4) = a1;
                }
            }
        }
        __syncthreads();
    }

    // ksum: deterministic 4-way reduce (one slot per (wave, d))
    sKsumP[w * 64 + kd] = ksum;
    __syncthreads();

    // write this block's partial KV_aug[65][68] d-major (row 64 = K_sum, pads 0)
    float* outp = partials + (size_t)b * KVSZ;
    for (int idx = tid; idx < KVSZ; idx += 256) {
        const int r = idx / KVLD;
        const int c = idx - r * KVLD;
        float val = 0.f;
        if (c < 64) {
            if (r < 64)
                val = sm.acc[idx];   // sm.acc is [d][v] stride 68 == same layout
            else
                val = sKsumP[c] + sKsumP[64 + c] + sKsumP[128 + c] + sKsumP[192 + c];
        }
        outp[idx] = val;
    }
}

// ---------------------------------------------------------------------------
// Reduce: sum the `split` partials per (n,h) -> kvt[nh][65][68]
// ---------------------------------------------------------------------------
__global__ __launch_bounds__(256)
void la_reduce(const float* __restrict__ partials, float* __restrict__ kvt, int split)
{
    const int idx = blockIdx.x * 256 + threadIdx.x;
    if (idx >= NH * KVSZ) return;
    const int nh  = idx / KVSZ;
    const int rem = idx - nh * KVSZ;
    const float* p = partials + (size_t)nh * split * KVSZ + rem;
    float s = 0.f;
    for (int c = 0; c < split; ++c) s += p[(size_t)c * KVSZ];
    kvt[idx] = s;
}

// ---------------------------------------------------------------------------
// Phase 2 (v5): register-tiled GEMM, Out[4096][65] = Qf[4096][64]*KV[64][65].
//  Per wave 64 rows x 32 cols, lane owns 8x4 tile; per k-chunk(4): 13
//  ds_read_b128 feed 160 FMAs; KV reused 8x, Q 4x in registers. Denominator
//  = KV row 64, accumulated per-lane for its own rows. Direct global stores.
//  (Round-6 measured ~20us ~= its 21us HBM floor -> unchanged.)
// ---------------------------------------------------------------------------
__global__ __launch_bounds__(256, 2)
void la_phase2(const float* __restrict__ Qin, const float* __restrict__ kvt,
               float* __restrict__ Out)
{
    __shared__ float sQ[128 * 68];   // 34.8 KB, row-major, stride 68
    __shared__ float sKV[KVSZ];      // 17.3 KB, [65][68] d-major

    const int b   = blockIdx.x;
    const int nh  = b >> 5;          // 32 l-chunks of 128 rows per (n,h)
    const int lc  = b & 31;
    const int n   = nh >> 3;
    const int h   = nh & 7;
    const int tid = threadIdx.x;
    const int w    = tid >> 6;
    const int lane = tid & 63;

    const float* Qc = Qin + (((size_t)n * L_L + (size_t)lc * 128) * H_H + h) * D_D;
    float*       Oc = Out + (((size_t)n * L_L + (size_t)lc * 128) * H_H + h) * D_D;

    // ---- stage KV_aug[65][68] into LDS (1105 float4, coalesced) ----
    {
        const float4* src = (const float4*)(kvt + (size_t)nh * KVSZ);
        float4*       dst = (float4*)sKV;
        #pragma unroll
        for (int it = 0; it < 4; ++it)
            dst[it * 256 + tid] = src[it * 256 + tid];
        if (tid < 81) dst[1024 + tid] = src[1024 + tid];
    }

    // ---- stage Q tile 128 rows x 64 cols (elu applied), stride 68 ----
    #pragma unroll
    for (int it = 0; it < 8; ++it) {
        const int slot = it * 256 + tid;   // 0..2047
        const int r    = slot >> 4;        // 0..127
        const int c4   = slot & 15;
        float4 v = *(const float4*)(Qc + (size_t)r * (H_H * D_D) + c4 * 4);
        v.x = elu1(v.x); v.y = elu1(v.y); v.z = elu1(v.z); v.w = elu1(v.w);
        *(float4*)&sQ[r * 68 + c4 * 4] = v;
    }
    __syncthreads();

    // ---- wave work assignment ----
    const int rt   = (w >> 1) * 64;        // row tile: 0 or 64
    const int wc   = w & 1;                // col half: 0 or 1
    const int rl   = lane & 7;             // row lane: rows rt + rl + 8j
    const int cg   = lane >> 3;            // col group
    const int ccol = wc * 32 + cg * 4;     // this lane's 4 output cols

    float acc[8][4];
    float den[8];
    #pragma unroll
    for (int j = 0; j < 8; ++j) {
        den[j] = 0.f;
        #pragma unroll
        for (int m = 0; m < 4; ++m) acc[j][m] = 0.f;
    }

    const int qbase = rt + rl;             // + 8j, stride-68 rows

    for (int kc = 0; kc < 16; ++kc) {
        // Q fragments: 8 rows x 4 k  (conflict-free b128: banks partition)
        float4 qv[8];
        #pragma unroll
        for (int j = 0; j < 8; ++j)
            qv[j] = *(const float4*)&sQ[(qbase + 8 * j) * 68 + kc * 4];
        // KV fragments: 4 k-rows x lane's 4 cols (conflict-free)
        const float4 kv0 = *(const float4*)&sKV[(kc * 4 + 0) * KVLD + ccol];
        const float4 kv1 = *(const float4*)&sKV[(kc * 4 + 1) * KVLD + ccol];
        const float4 kv2 = *(const float4*)&sKV[(kc * 4 + 2) * KVLD + ccol];
        const float4 kv3 = *(const float4*)&sKV[(kc * 4 + 3) * KVLD + ccol];
        // K_sum fragment: wave-uniform broadcast
        const float4 ks  = *(const float4*)&sKV[64 * KVLD + kc * 4];

        #pragma unroll
        for (int j = 0; j < 8; ++j) {
            const float q0 = qv[j].x, q1 = qv[j].y, q2 = qv[j].z, q3 = qv[j].w;
            den[j] = fmaf(q0, ks.x, den[j]);
            den[j] = fmaf(q1, ks.y, den[j]);
            den[j] = fmaf(q2, ks.z, den[j]);
            den[j] = fmaf(q3, ks.w, den[j]);
            acc[j][0] = fmaf(q0, kv0.x, acc[j][0]);
            acc[j][0] = fmaf(q1, kv1.x, acc[j][0]);
            acc[j][0] = fmaf(q2, kv2.x, acc[j][0]);
            acc[j][0] = fmaf(q3, kv3.x, acc[j][0]);
            acc[j][1] = fmaf(q0, kv0.y, acc[j][1]);
            acc[j][1] = fmaf(q1, kv1.y, acc[j][1]);
            acc[j][1] = fmaf(q2, kv2.y, acc[j][1]);
            acc[j][1] = fmaf(q3, kv3.y, acc[j][1]);
            acc[j][2] = fmaf(q0, kv0.z, acc[j][2]);
            acc[j][2] = fmaf(q1, kv1.z, acc[j][2]);
            acc[j][2] = fmaf(q2, kv2.z, acc[j][2]);
            acc[j][2] = fmaf(q3, kv3.z, acc[j][2]);
            acc[j][3] = fmaf(q0, kv0.w, acc[j][3]);
            acc[j][3] = fmaf(q1, kv1.w, acc[j][3]);
            acc[j][3] = fmaf(q2, kv2.w, acc[j][3]);
            acc[j][3] = fmaf(q3, kv3.w, acc[j][3]);
        }
    }

    // ---- epilogue: scale by 1/(den+eps), direct coalesced global stores ----
    #pragma unroll
    for (int j = 0; j < 8; ++j) {
        const float rz = 1.0f / (den[j] + 1e-6f);
        *(float4*)(Oc + (size_t)(qbase + 8 * j) * (H_H * D_D) + ccol) =
            make_float4(acc[j][0] * rz, acc[j][1] * rz,
                        acc[j][2] * rz, acc[j][3] * rz);
    }
}

// ---------------------------------------------------------------------------
extern "C" void kernel_launch(void* const* d_in, const int* in_sizes, int n_in,
                              void* d_out, int out_size, void* d_ws, size_t ws_size,
                              hipStream_t stream)
{
    const float* Q = (const float*)d_in[0];
    const float* K = (const float*)d_in[1];
    const float* V = (const float*)d_in[2];
    float* out = (float*)d_out;

    // ws layout: [ kvt: NH*KVSZ floats ][ partials: NH*split*KVSZ floats ]
    float* kvt = (float*)d_ws;
    const size_t kvt_bytes = (size_t)NH * KVSZ * sizeof(float);

    int split = 16;
    while (split > 1 &&
           kvt_bytes + (size_t)NH * split * KVSZ * sizeof(float) > ws_size)
        split >>= 1;
    float* partials = kvt + (size_t)NH * KVSZ;
    const int schunk = S_S / split;

    la_phase1<<<NH * split, 256, 0, stream>>>(K, V, partials, split, schunk);

    const int red_blocks = (NH * KVSZ + 255) / 256;   // 1105 exactly
    la_reduce<<<red_blocks, 256, 0, stream>>>(partials, kvt, split);

    la_phase2<<<NH * (L_L / 128), 256, 0, stream>>>(Q, kvt, out);
}

// Round 12
// 98.744 us; speedup vs baseline: 2.1291x; 2.1291x over previous
//
#include <hip/hip_runtime.h>
#include <hip/hip_bf16.h>
#include <cstddef>
#include <cstdint>

// Problem constants (fixed by the reference setup)
#define N_B   8
#define L_L   4096
#define S_S   4096
#define H_H   8
#define D_D   64
#define NH    64          // N_B * H_H
// KV_aug layout (d-major): rows 0..63 = KV[d][v] (stride 68, cols 64..67 pad),
// row 64 = K_sum[d] (indexed by d in cols 0..63). KVSZ floats per (n,h).
#define KVLD  68
#define KVSZ  (65 * KVLD)   // 4420

typedef const float __attribute__((address_space(1)))* gas_fp;
typedef float __attribute__((address_space(3)))* las_fp;

__device__ __forceinline__ float elu1(float x) {
    // elu(x)+1 : x>0 ? x+1 : exp(x)
    return x > 0.f ? x + 1.f : __expf(x);
}

// ---------------------------------------------------------------------------
// Phase 1 (v7): wave-private, zero-barrier loop (v5 structure) + two fixes.
//  Ledger: v5 = 77us, NO spill, two diagnosed costs: (a) K ds_write map
//  ((tid&3)*64B -> 8-way bank conflict, 12.8M ~= 20us), (b) V latency fully
//  exposed (vmcnt(0) right after issue). v6 (elu-at-read + full unroll)
//  re-spilled (WRITE 245MB) -> reverted.
//  v7 = v5 register profile EXACTLY (K reg-staged, elu at staging = once per
//  element, unroll-4 compute) with:
//   1. lane-linear K staging map (chunk_base + lane*16B) -> conflict-free
//      ds_write_b128 (same layout the V-DMA hardware uses).
//   2. V double-buffered via global_load_lds (zero held regs): issue V(t+1)
//      after K(t)'s loads, s_waitcnt vmcnt(4) keeps V(t+1) in flight while
//      guaranteeing V(t) (older than K(t), already compiler-waited) arrived.
//  Wave w owns s-rows w*16..w*16+15 of each 64-row tile; all LDS traffic in
//  the loop is wave-private -> no __syncthreads until the epilogue (whose
//  implicit vmcnt(0) also fences the last in-flight DMAs before acc aliasing).
// ---------------------------------------------------------------------------
__global__ __launch_bounds__(256, 3)
void la_phase1(const float* __restrict__ Kin, const float* __restrict__ Vin,
               float* __restrict__ partials, int split, int schunk)
{
    __shared__ union {
        struct { float K[64 * 64]; float V[2][64 * 64]; } st;  // 48 KB
        float acc[64 * 68];                                    // 17.3 KB
    } sm;
    __shared__ float sKsumP[4 * 64];     // per-wave ksum partials

    const int b     = blockIdx.x;
    const int nh    = b / split;
    const int chunk = b - nh * split;
    const int n     = nh >> 3;
    const int h     = nh & 7;
    const int s0    = chunk * schunk;

    const int tid  = threadIdx.x;
    const int w    = tid >> 6;
    const int lane = tid & 63;
    const int dg   = lane >> 3;   // d-group: d = dg*8 + i
    const int vg   = lane & 7;    // v-group: v = vg*8 + j

    float acc[8][8];
    #pragma unroll
    for (int i = 0; i < 8; ++i)
        #pragma unroll
        for (int j = 0; j < 8; ++j) acc[i][j] = 0.f;
    float ksum = 0.f;

    const int kd = lane;               // ksum d index (per-wave full coverage)

    // staging map (wave-private, lane-linear within each 1024B chunk):
    // chunk c covers rows w*16+c*4 .. +3; lane l -> row +(l>>4), col (l&15)*4
    const int lrow = lane >> 4;        // 0..3
    const int lcol = (lane & 15) * 4;  // float col

    const float* Kb = Kin + (size_t)n * S_S * (H_H * D_D) + h * D_D;
    const float* Vb = Vin + (size_t)n * S_S * (H_H * D_D) + h * D_D;

    const int ntiles = schunk >> 6;    // tiles of 64 s-rows

    // ---- prologue: issue V(0) DMA (4 chunks, zero regs held) ----
    #pragma unroll
    for (int c = 0; c < 4; ++c) {
        const int r = w * 16 + c * 4 + lrow;
        __builtin_amdgcn_global_load_lds(
            (gas_fp)(Vb + (size_t)(s0 + r) * (H_H * D_D) + lcol),
            (las_fp)&sm.st.V[0][(w * 16 + c * 4) * 64], 16, 0, 0);
    }

    for (int t = 0; t < ntiles; ++t) {
        const int srow = s0 + t * 64;

        // ---- K(t): load -> elu -> lane-linear write (conflict-free) ----
        // (loads issued first so they are OLDER than V(t+1)'s DMAs; the
        // compiler's own wait for K data then leaves V(t+1) in flight)
        #pragma unroll
        for (int c = 0; c < 4; ++c) {
            const int r = w * 16 + c * 4 + lrow;
            float4 kv = *(const float4*)(Kb + (size_t)(srow + r) * (H_H * D_D) + lcol);
            kv.x = elu1(kv.x); kv.y = elu1(kv.y);
            kv.z = elu1(kv.z); kv.w = elu1(kv.w);
            *(float4*)&sm.st.K[(w * 16 + c * 4) * 64 + lane * 4] = kv;
        }

        // ---- issue V(t+1) DMA into the other buffer ----
        if (t + 1 < ntiles) {
            const int srn = srow + 64;
            #pragma unroll
            for (int c = 0; c < 4; ++c) {
                const int r = w * 16 + c * 4 + lrow;
                __builtin_amdgcn_global_load_lds(
                    (gas_fp)(Vb + (size_t)(srn + r) * (H_H * D_D) + lcol),
                    (las_fp)&sm.st.V[(t & 1) ^ 1][(w * 16 + c * 4) * 64], 16, 0, 0);
            }
            // <=4 outstanding: V(t+1) may remain, V(t) & K(t) guaranteed done
            asm volatile("s_waitcnt vmcnt(4)" ::: "memory");
        } else {
            asm volatile("s_waitcnt vmcnt(0)" ::: "memory");
        }

        const float* Kbuf = sm.st.K;
        const float* Vbuf = sm.st.V[t & 1];

        // ---- compute: wave w owns s-rows w*16 .. w*16+15 ----
        #pragma unroll 4
        for (int sl = 0; sl < 16; ++sl) {
            const int s = w * 16 + sl;
            const float4 k0 = *(const float4*)&Kbuf[s * 64 + dg * 8];
            const float4 k1 = *(const float4*)&Kbuf[s * 64 + dg * 8 + 4];
            const float4 v0 = *(const float4*)&Vbuf[s * 64 + vg * 8];
            const float4 v1 = *(const float4*)&Vbuf[s * 64 + vg * 8 + 4];
            const float kf[8] = {k0.x, k0.y, k0.z, k0.w, k1.x, k1.y, k1.z, k1.w};
            const float vf[8] = {v0.x, v0.y, v0.z, v0.w, v1.x, v1.y, v1.z, v1.w};
            #pragma unroll
            for (int i = 0; i < 8; ++i)
                #pragma unroll
                for (int j = 0; j < 8; ++j)
                    acc[i][j] = fmaf(kf[i], vf[j], acc[i][j]);
        }
        // K_sum partial over the same 16 rows (elu'd values in LDS; 2 lanes
        // per bank = free)
        #pragma unroll
        for (int sl = 0; sl < 16; ++sl)
            ksum += Kbuf[(w * 16 + sl) * 64 + kd];
    }
    __syncthreads();   // loop done (implicit vmcnt(0) drains DMAs); acc safe

    // cross-wave reduce of acc into sm.acc[d][v] (stride 68), sequential & exact
    for (int ww = 0; ww < 4; ++ww) {
        if (w == ww) {
            #pragma unroll
            for (int i = 0; i < 8; ++i) {
                float* p = &sm.acc[(dg * 8 + i) * 68 + vg * 8];
                if (ww == 0) {
                    *(float4*)p       = make_float4(acc[i][0], acc[i][1], acc[i][2], acc[i][3]);
                    *(float4*)(p + 4) = make_float4(acc[i][4], acc[i][5], acc[i][6], acc[i][7]);
                } else {
                    float4 a0 = *(const float4*)p;
                    float4 a1 = *(const float4*)(p + 4);
                    a0.x += acc[i][0]; a0.y += acc[i][1]; a0.z += acc[i][2]; a0.w += acc[i][3];
                    a1.x += acc[i][4]; a1.y += acc[i][5]; a1.z += acc[i][6]; a1.w += acc[i][7];
                    *(float4*)p       = a0;
                    *(float4*)(p + 4) = a1;
                }
            }
        }
        __syncthreads();
    }

    // ksum: deterministic 4-way reduce (one slot per (wave, d))
    sKsumP[w * 64 + kd] = ksum;
    __syncthreads();

    // write this block's partial KV_aug[65][68] d-major (row 64 = K_sum, pads 0)
    float* outp = partials + (size_t)b * KVSZ;
    for (int idx = tid; idx < KVSZ; idx += 256) {
        const int r = idx / KVLD;
        const int c = idx - r * KVLD;
        float val = 0.f;
        if (c < 64) {
            if (r < 64)
                val = sm.acc[idx];   // sm.acc is [d][v] stride 68 == same layout
            else
                val = sKsumP[c] + sKsumP[64 + c] + sKsumP[128 + c] + sKsumP[192 + c];
        }
        outp[idx] = val;
    }
}

// ---------------------------------------------------------------------------
// Reduce: sum the `split` partials per (n,h) -> kvt[nh][65][68]
// ---------------------------------------------------------------------------
__global__ __launch_bounds__(256)
void la_reduce(const float* __restrict__ partials, float* __restrict__ kvt, int split)
{
    const int idx = blockIdx.x * 256 + threadIdx.x;
    if (idx >= NH * KVSZ) return;
    const int nh  = idx / KVSZ;
    const int rem = idx - nh * KVSZ;
    const float* p = partials + (size_t)nh * split * KVSZ + rem;
    float s = 0.f;
    for (int c = 0; c < split; ++c) s += p[(size_t)c * KVSZ];
    kvt[idx] = s;
}

// ---------------------------------------------------------------------------
// Phase 2 (v5): register-tiled GEMM, Out[4096][65] = Qf[4096][64]*KV[64][65].
//  Per wave 64 rows x 32 cols, lane owns 8x4 tile; per k-chunk(4): 13
//  ds_read_b128 feed 160 FMAs; KV reused 8x, Q 4x in registers. Denominator
//  = KV row 64, accumulated per-lane for its own rows. Direct global stores.
//  (Round-6 measured ~20us ~= its 21us HBM floor -> unchanged.)
// ---------------------------------------------------------------------------
__global__ __launch_bounds__(256, 2)
void la_phase2(const float* __restrict__ Qin, const float* __restrict__ kvt,
               float* __restrict__ Out)
{
    __shared__ float sQ[128 * 68];   // 34.8 KB, row-major, stride 68
    __shared__ float sKV[KVSZ];      // 17.3 KB, [65][68] d-major

    const int b   = blockIdx.x;
    const int nh  = b >> 5;          // 32 l-chunks of 128 rows per (n,h)
    const int lc  = b & 31;
    const int n   = nh >> 3;
    const int h   = nh & 7;
    const int tid = threadIdx.x;
    const int w    = tid >> 6;
    const int lane = tid & 63;

    const float* Qc = Qin + (((size_t)n * L_L + (size_t)lc * 128) * H_H + h) * D_D;
    float*       Oc = Out + (((size_t)n * L_L + (size_t)lc * 128) * H_H + h) * D_D;

    // ---- stage KV_aug[65][68] into LDS (1105 float4, coalesced) ----
    {
        const float4* src = (const float4*)(kvt + (size_t)nh * KVSZ);
        float4*       dst = (float4*)sKV;
        #pragma unroll
        for (int it = 0; it < 4; ++it)
            dst[it * 256 + tid] = src[it * 256 + tid];
        if (tid < 81) dst[1024 + tid] = src[1024 + tid];
    }

    // ---- stage Q tile 128 rows x 64 cols (elu applied), stride 68 ----
    #pragma unroll
    for (int it = 0; it < 8; ++it) {
        const int slot = it * 256 + tid;   // 0..2047
        const int r    = slot >> 4;        // 0..127
        const int c4   = slot & 15;
        float4 v = *(const float4*)(Qc + (size_t)r * (H_H * D_D) + c4 * 4);
        v.x = elu1(v.x); v.y = elu1(v.y); v.z = elu1(v.z); v.w = elu1(v.w);
        *(float4*)&sQ[r * 68 + c4 * 4] = v;
    }
    __syncthreads();

    // ---- wave work assignment ----
    const int rt   = (w >> 1) * 64;        // row tile: 0 or 64
    const int wc   = w & 1;                // col half: 0 or 1
    const int rl   = lane & 7;             // row lane: rows rt + rl + 8j
    const int cg   = lane >> 3;            // col group
    const int ccol = wc * 32 + cg * 4;     // this lane's 4 output cols

    float acc[8][4];
    float den[8];
    #pragma unroll
    for (int j = 0; j < 8; ++j) {
        den[j] = 0.f;
        #pragma unroll
        for (int m = 0; m < 4; ++m) acc[j][m] = 0.f;
    }

    const int qbase = rt + rl;             // + 8j, stride-68 rows

    for (int kc = 0; kc < 16; ++kc) {
        // Q fragments: 8 rows x 4 k  (conflict-free b128: banks partition)
        float4 qv[8];
        #pragma unroll
        for (int j = 0; j < 8; ++j)
            qv[j] = *(const float4*)&sQ[(qbase + 8 * j) * 68 + kc * 4];
        // KV fragments: 4 k-rows x lane's 4 cols (conflict-free)
        const float4 kv0 = *(const float4*)&sKV[(kc * 4 + 0) * KVLD + ccol];
        const float4 kv1 = *(const float4*)&sKV[(kc * 4 + 1) * KVLD + ccol];
        const float4 kv2 = *(const float4*)&sKV[(kc * 4 + 2) * KVLD + ccol];
        const float4 kv3 = *(const float4*)&sKV[(kc * 4 + 3) * KVLD + ccol];
        // K_sum fragment: wave-uniform broadcast
        const float4 ks  = *(const float4*)&sKV[64 * KVLD + kc * 4];

        #pragma unroll
        for (int j = 0; j < 8; ++j) {
            const float q0 = qv[j].x, q1 = qv[j].y, q2 = qv[j].z, q3 = qv[j].w;
            den[j] = fmaf(q0, ks.x, den[j]);
            den[j] = fmaf(q1, ks.y, den[j]);
            den[j] = fmaf(q2, ks.z, den[j]);
            den[j] = fmaf(q3, ks.w, den[j]);
            acc[j][0] = fmaf(q0, kv0.x, acc[j][0]);
            acc[j][0] = fmaf(q1, kv1.x, acc[j][0]);
            acc[j][0] = fmaf(q2, kv2.x, acc[j][0]);
            acc[j][0] = fmaf(q3, kv3.x, acc[j][0]);
            acc[j][1] = fmaf(q0, kv0.y, acc[j][1]);
            acc[j][1] = fmaf(q1, kv1.y, acc[j][1]);
            acc[j][1] = fmaf(q2, kv2.y, acc[j][1]);
            acc[j][1] = fmaf(q3, kv3.y, acc[j][1]);
            acc[j][2] = fmaf(q0, kv0.z, acc[j][2]);
            acc[j][2] = fmaf(q1, kv1.z, acc[j][2]);
            acc[j][2] = fmaf(q2, kv2.z, acc[j][2]);
            acc[j][2] = fmaf(q3, kv3.z, acc[j][2]);
            acc[j][3] = fmaf(q0, kv0.w, acc[j][3]);
            acc[j][3] = fmaf(q1, kv1.w, acc[j][3]);
            acc[j][3] = fmaf(q2, kv2.w, acc[j][3]);
            acc[j][3] = fmaf(q3, kv3.w, acc[j][3]);
        }
    }

    // ---- epilogue: scale by 1/(den+eps), direct coalesced global stores ----
    #pragma unroll
    for (int j = 0; j < 8; ++j) {
        const float rz = 1.0f / (den[j] + 1e-6f);
        *(float4*)(Oc + (size_t)(qbase + 8 * j) * (H_H * D_D) + ccol) =
            make_float4(acc[j][0] * rz, acc[j][1] * rz,
                        acc[j][2] * rz, acc[j][3] * rz);
    }
}

// ---------------------------------------------------------------------------
extern "C" void kernel_launch(void* const* d_in, const int* in_sizes, int n_in,
                              void* d_out, int out_size, void* d_ws, size_t ws_size,
                              hipStream_t stream)
{
    const float* Q = (const float*)d_in[0];
    const float* K = (const float*)d_in[1];
    const float* V = (const float*)d_in[2];
    float* out = (float*)d_out;

    // ws layout: [ kvt: NH*KVSZ floats ][ partials: NH*split*KVSZ floats ]
    float* kvt = (float*)d_ws;
    const size_t kvt_bytes = (size_t)NH * KVSZ * sizeof(float);

    int split = 16;
    while (split > 1 &&
           kvt_bytes + (size_t)NH * split * KVSZ * sizeof(float) > ws_size)
        split >>= 1;
    float* partials = kvt + (size_t)NH * KVSZ;
    const int schunk = S_S / split;

    la_phase1<<<NH * split, 256, 0, stream>>>(K, V, partials, split, schunk);

    const int red_blocks = (NH * KVSZ + 255) / 256;   // 1105 exactly
    la_reduce<<<red_blocks, 256, 0, stream>>>(partials, kvt, split);

    la_phase2<<<NH * (L_L / 128), 256, 0, stream>>>(Q, kvt, out);
}

// Round 13
// 97.185 us; speedup vs baseline: 2.1632x; 1.0160x over previous
//
#include <hip/hip_runtime.h>
#include <hip/hip_bf16.h>
#include <cstddef>
#include <cstdint>

// Problem constants (fixed by the reference setup)
#define N_B   8
#define L_L   4096
#define S_S   4096
#define H_H   8
#define D_D   64
#define NH    64          // N_B * H_H
// KV_aug layout (d-major): rows 0..63 = KV[d][v] (stride 68, cols 64..67 pad),
// row 64 = K_sum[d] (indexed by d in cols 0..63). KVSZ floats per (n,h).
#define KVLD  68
#define KVSZ  (65 * KVLD)   // 4420

typedef const float __attribute__((address_space(1)))* gas_fp;
typedef float __attribute__((address_space(3)))* las_fp;

__device__ __forceinline__ float elu1(float x) {
    // elu(x)+1 : x>0 ? x+1 : exp(x)
    return x > 0.f ? x + 1.f : __expf(x);
}

// ---------------------------------------------------------------------------
// Phase 1 (v8): v7 structure with TILE 64->32 for 4-blocks/CU residency.
//  v7 ledger: 68us, no spill (FETCH 66MB), conflicts fixed (12.8M->2.3M,
//  residual = epilogue), but LDS 50KB -> 3 blocks/CU while grid = 4/CU:
//  serial 4th-block tail (+33%) and only 3 waves/SIMD for latency hiding
//  (Occ 22.6%, VALU 30%).
//  v8: TILE=32 -> LDS 25.9KB -> ALL 4 blocks/CU resident (no tail), 4
//  waves/SIMD. launch_bounds(256,4) = cap 128 vs 84 measured (no-spill
//  margin). Same wave-private zero-barrier loop: wave w owns s-rows
//  w*8..w*8+7/tile; K reg-staged (elu at staging, lane-linear conflict-free
//  write); V double-buffered global_load_lds DMA, vmcnt(2) keeps V(t+1) in
//  flight across compute.
// ---------------------------------------------------------------------------
__global__ __launch_bounds__(256, 4)
void la_phase1(const float* __restrict__ Kin, const float* __restrict__ Vin,
               float* __restrict__ partials, int split, int schunk)
{
    __shared__ union {
        struct { float K[32 * 64]; float V[2][32 * 64]; } st;  // 24 KB
        float acc[64 * 68];                                    // 17.3 KB
    } sm;
    __shared__ float sKsumP[4 * 64];     // per-wave ksum partials

    const int b     = blockIdx.x;
    const int nh    = b / split;
    const int chunk = b - nh * split;
    const int n     = nh >> 3;
    const int h     = nh & 7;
    const int s0    = chunk * schunk;

    const int tid  = threadIdx.x;
    const int w    = tid >> 6;
    const int lane = tid & 63;
    const int dg   = lane >> 3;   // d-group: d = dg*8 + i
    const int vg   = lane & 7;    // v-group: v = vg*8 + j

    float acc[8][8];
    #pragma unroll
    for (int i = 0; i < 8; ++i)
        #pragma unroll
        for (int j = 0; j < 8; ++j) acc[i][j] = 0.f;
    float ksum = 0.f;

    const int kd = lane;               // ksum d index (per-wave full coverage)

    // staging map (wave-private, lane-linear within each 1024B chunk):
    // chunk c covers rows w*8+c*4 .. +3; lane l -> row +(l>>4), col (l&15)*4
    const int lrow = lane >> 4;        // 0..3
    const int lcol = (lane & 15) * 4;  // float col

    const float* Kb = Kin + (size_t)n * S_S * (H_H * D_D) + h * D_D;
    const float* Vb = Vin + (size_t)n * S_S * (H_H * D_D) + h * D_D;

    const int ntiles = schunk >> 5;    // tiles of 32 s-rows (8 at split=16)

    // ---- prologue: issue V(0) DMA (2 chunks, zero regs held) ----
    #pragma unroll
    for (int c = 0; c < 2; ++c) {
        const int r = w * 8 + c * 4 + lrow;
        __builtin_amdgcn_global_load_lds(
            (gas_fp)(Vb + (size_t)(s0 + r) * (H_H * D_D) + lcol),
            (las_fp)&sm.st.V[0][(w * 8 + c * 4) * 64], 16, 0, 0);
    }

    for (int t = 0; t < ntiles; ++t) {
        const int srow = s0 + t * 32;

        // ---- K(t): load -> elu -> lane-linear write (conflict-free) ----
        #pragma unroll
        for (int c = 0; c < 2; ++c) {
            const int r = w * 8 + c * 4 + lrow;
            float4 kv = *(const float4*)(Kb + (size_t)(srow + r) * (H_H * D_D) + lcol);
            kv.x = elu1(kv.x); kv.y = elu1(kv.y);
            kv.z = elu1(kv.z); kv.w = elu1(kv.w);
            *(float4*)&sm.st.K[(w * 8 + c * 4) * 64 + lane * 4] = kv;
        }

        // ---- issue V(t+1) DMA into the other buffer ----
        if (t + 1 < ntiles) {
            const int srn = srow + 32;
            #pragma unroll
            for (int c = 0; c < 2; ++c) {
                const int r = w * 8 + c * 4 + lrow;
                __builtin_amdgcn_global_load_lds(
                    (gas_fp)(Vb + (size_t)(srn + r) * (H_H * D_D) + lcol),
                    (las_fp)&sm.st.V[(t & 1) ^ 1][(w * 8 + c * 4) * 64], 16, 0, 0);
            }
            // <=2 outstanding: V(t+1) may remain; V(t) & K(t) guaranteed done
            asm volatile("s_waitcnt vmcnt(2)" ::: "memory");
        } else {
            asm volatile("s_waitcnt vmcnt(0)" ::: "memory");
        }

        const float* Kbuf = sm.st.K;
        const float* Vbuf = sm.st.V[t & 1];

        // ---- compute: wave w owns s-rows w*8 .. w*8+7 ----
        #pragma unroll
        for (int sl = 0; sl < 8; ++sl) {
            const int s = w * 8 + sl;
            const float4 k0 = *(const float4*)&Kbuf[s * 64 + dg * 8];
            const float4 k1 = *(const float4*)&Kbuf[s * 64 + dg * 8 + 4];
            const float4 v0 = *(const float4*)&Vbuf[s * 64 + vg * 8];
            const float4 v1 = *(const float4*)&Vbuf[s * 64 + vg * 8 + 4];
            const float kf[8] = {k0.x, k0.y, k0.z, k0.w, k1.x, k1.y, k1.z, k1.w};
            const float vf[8] = {v0.x, v0.y, v0.z, v0.w, v1.x, v1.y, v1.z, v1.w};
            #pragma unroll
            for (int i = 0; i < 8; ++i)
                #pragma unroll
                for (int j = 0; j < 8; ++j)
                    acc[i][j] = fmaf(kf[i], vf[j], acc[i][j]);
        }
        // K_sum partial over the same 8 rows (elu'd values in LDS; stride-1
        // b32 reads = 2 lanes/bank = free)
        #pragma unroll
        for (int sl = 0; sl < 8; ++sl)
            ksum += Kbuf[(w * 8 + sl) * 64 + kd];
    }
    __syncthreads();   // loop done (implicit vmcnt(0) drains DMAs); acc safe

    // cross-wave reduce of acc into sm.acc[d][v] (stride 68), sequential & exact
    for (int ww = 0; ww < 4; ++ww) {
        if (w == ww) {
            #pragma unroll
            for (int i = 0; i < 8; ++i) {
                float* p = &sm.acc[(dg * 8 + i) * 68 + vg * 8];
                if (ww == 0) {
                    *(float4*)p       = make_float4(acc[i][0], acc[i][1], acc[i][2], acc[i][3]);
                    *(float4*)(p + 4) = make_float4(acc[i][4], acc[i][5], acc[i][6], acc[i][7]);
                } else {
                    float4 a0 = *(const float4*)p;
                    float4 a1 = *(const float4*)(p + 4);
                    a0.x += acc[i][0]; a0.y += acc[i][1]; a0.z += acc[i][2]; a0.w += acc[i][3];
                    a1.x += acc[i][4]; a1.y += acc[i][5]; a1.z += acc[i][6]; a1.w += acc[i][7];
                    *(float4*)p       = a0;
                    *(float4*)(p + 4) = a1;
                }
            }
        }
        __syncthreads();
    }

    // ksum: deterministic 4-way reduce (one slot per (wave, d))
    sKsumP[w * 64 + kd] = ksum;
    __syncthreads();

    // write this block's partial KV_aug[65][68] d-major (row 64 = K_sum, pads 0)
    float* outp = partials + (size_t)b * KVSZ;
    for (int idx = tid; idx < KVSZ; idx += 256) {
        const int r = idx / KVLD;
        const int c = idx - r * KVLD;
        float val = 0.f;
        if (c < 64) {
            if (r < 64)
                val = sm.acc[idx];   // sm.acc is [d][v] stride 68 == same layout
            else
                val = sKsumP[c] + sKsumP[64 + c] + sKsumP[128 + c] + sKsumP[192 + c];
        }
        outp[idx] = val;
    }
}

// ---------------------------------------------------------------------------
// Reduce: sum the `split` partials per (n,h) -> kvt[nh][65][68]
// ---------------------------------------------------------------------------
__global__ __launch_bounds__(256)
void la_reduce(const float* __restrict__ partials, float* __restrict__ kvt, int split)
{
    const int idx = blockIdx.x * 256 + threadIdx.x;
    if (idx >= NH * KVSZ) return;
    const int nh  = idx / KVSZ;
    const int rem = idx - nh * KVSZ;
    const float* p = partials + (size_t)nh * split * KVSZ + rem;
    float s = 0.f;
    for (int c = 0; c < split; ++c) s += p[(size_t)c * KVSZ];
    kvt[idx] = s;
}

// ---------------------------------------------------------------------------
// Phase 2 (v5): register-tiled GEMM, Out[4096][65] = Qf[4096][64]*KV[64][65].
//  Per wave 64 rows x 32 cols, lane owns 8x4 tile; per k-chunk(4): 13
//  ds_read_b128 feed 160 FMAs; KV reused 8x, Q 4x in registers. Denominator
//  = KV row 64, accumulated per-lane for its own rows. Direct global stores.
//  (Round-6 measured ~20us ~= its 21us HBM floor -> unchanged.)
// ---------------------------------------------------------------------------
__global__ __launch_bounds__(256, 2)
void la_phase2(const float* __restrict__ Qin, const float* __restrict__ kvt,
               float* __restrict__ Out)
{
    __shared__ float sQ[128 * 68];   // 34.8 KB, row-major, stride 68
    __shared__ float sKV[KVSZ];      // 17.3 KB, [65][68] d-major

    const int b   = blockIdx.x;
    const int nh  = b >> 5;          // 32 l-chunks of 128 rows per (n,h)
    const int lc  = b & 31;
    const int n   = nh >> 3;
    const int h   = nh & 7;
    const int tid = threadIdx.x;
    const int w    = tid >> 6;
    const int lane = tid & 63;

    const float* Qc = Qin + (((size_t)n * L_L + (size_t)lc * 128) * H_H + h) * D_D;
    float*       Oc = Out + (((size_t)n * L_L + (size_t)lc * 128) * H_H + h) * D_D;

    // ---- stage KV_aug[65][68] into LDS (1105 float4, coalesced) ----
    {
        const float4* src = (const float4*)(kvt + (size_t)nh * KVSZ);
        float4*       dst = (float4*)sKV;
        #pragma unroll
        for (int it = 0; it < 4; ++it)
            dst[it * 256 + tid] = src[it * 256 + tid];
        if (tid < 81) dst[1024 + tid] = src[1024 + tid];
    }

    // ---- stage Q tile 128 rows x 64 cols (elu applied), stride 68 ----
    #pragma unroll
    for (int it = 0; it < 8; ++it) {
        const int slot = it * 256 + tid;   // 0..2047
        const int r    = slot >> 4;        // 0..127
        const int c4   = slot & 15;
        float4 v = *(const float4*)(Qc + (size_t)r * (H_H * D_D) + c4 * 4);
        v.x = elu1(v.x); v.y = elu1(v.y); v.z = elu1(v.z); v.w = elu1(v.w);
        *(float4*)&sQ[r * 68 + c4 * 4] = v;
    }
    __syncthreads();

    // ---- wave work assignment ----
    const int rt   = (w >> 1) * 64;        // row tile: 0 or 64
    const int wc   = w & 1;                // col half: 0 or 1
    const int rl   = lane & 7;             // row lane: rows rt + rl + 8j
    const int cg   = lane >> 3;            // col group
    const int ccol = wc * 32 + cg * 4;     // this lane's 4 output cols

    float acc[8][4];
    float den[8];
    #pragma unroll
    for (int j = 0; j < 8; ++j) {
        den[j] = 0.f;
        #pragma unroll
        for (int m = 0; m < 4; ++m) acc[j][m] = 0.f;
    }

    const int qbase = rt + rl;             // + 8j, stride-68 rows

    for (int kc = 0; kc < 16; ++kc) {
        // Q fragments: 8 rows x 4 k  (conflict-free b128: banks partition)
        float4 qv[8];
        #pragma unroll
        for (int j = 0; j < 8; ++j)
            qv[j] = *(const float4*)&sQ[(qbase + 8 * j) * 68 + kc * 4];
        // KV fragments: 4 k-rows x lane's 4 cols (conflict-free)
        const float4 kv0 = *(const float4*)&sKV[(kc * 4 + 0) * KVLD + ccol];
        const float4 kv1 = *(const float4*)&sKV[(kc * 4 + 1) * KVLD + ccol];
        const float4 kv2 = *(const float4*)&sKV[(kc * 4 + 2) * KVLD + ccol];
        const float4 kv3 = *(const float4*)&sKV[(kc * 4 + 3) * KVLD + ccol];
        // K_sum fragment: wave-uniform broadcast
        const float4 ks  = *(const float4*)&sKV[64 * KVLD + kc * 4];

        #pragma unroll
        for (int j = 0; j < 8; ++j) {
            const float q0 = qv[j].x, q1 = qv[j].y, q2 = qv[j].z, q3 = qv[j].w;
            den[j] = fmaf(q0, ks.x, den[j]);
            den[j] = fmaf(q1, ks.y, den[j]);
            den[j] = fmaf(q2, ks.z, den[j]);
            den[j] = fmaf(q3, ks.w, den[j]);
            acc[j][0] = fmaf(q0, kv0.x, acc[j][0]);
            acc[j][0] = fmaf(q1, kv1.x, acc[j][0]);
            acc[j][0] = fmaf(q2, kv2.x, acc[j][0]);
            acc[j][0] = fmaf(q3, kv3.x, acc[j][0]);
            acc[j][1] = fmaf(q0, kv0.y, acc[j][1]);
            acc[j][1] = fmaf(q1, kv1.y, acc[j][1]);
            acc[j][1] = fmaf(q2, kv2.y, acc[j][1]);
            acc[j][1] = fmaf(q3, kv3.y, acc[j][1]);
            acc[j][2] = fmaf(q0, kv0.z, acc[j][2]);
            acc[j][2] = fmaf(q1, kv1.z, acc[j][2]);
            acc[j][2] = fmaf(q2, kv2.z, acc[j][2]);
            acc[j][2] = fmaf(q3, kv3.z, acc[j][2]);
            acc[j][3] = fmaf(q0, kv0.w, acc[j][3]);
            acc[j][3] = fmaf(q1, kv1.w, acc[j][3]);
            acc[j][3] = fmaf(q2, kv2.w, acc[j][3]);
            acc[j][3] = fmaf(q3, kv3.w, acc[j][3]);
        }
    }

    // ---- epilogue: scale by 1/(den+eps), direct coalesced global stores ----
    #pragma unroll
    for (int j = 0; j < 8; ++j) {
        const float rz = 1.0f / (den[j] + 1e-6f);
        *(float4*)(Oc + (size_t)(qbase + 8 * j) * (H_H * D_D) + ccol) =
            make_float4(acc[j][0] * rz, acc[j][1] * rz,
                        acc[j][2] * rz, acc[j][3] * rz);
    }
}

// ---------------------------------------------------------------------------
extern "C" void kernel_launch(void* const* d_in, const int* in_sizes, int n_in,
                              void* d_out, int out_size, void* d_ws, size_t ws_size,
                              hipStream_t stream)
{
    const float* Q = (const float*)d_in[0];
    const float* K = (const float*)d_in[1];
    const float* V = (const float*)d_in[2];
    float* out = (float*)d_out;

    // ws layout: [ kvt: NH*KVSZ floats ][ partials: NH*split*KVSZ floats ]
    float* kvt = (float*)d_ws;
    const size_t kvt_bytes = (size_t)NH * KVSZ * sizeof(float);

    int split = 16;
    while (split > 1 &&
           kvt_bytes + (size_t)NH * split * KVSZ * sizeof(float) > ws_size)
        split >>= 1;
    float* partials = kvt + (size_t)NH * KVSZ;
    const int schunk = S_S / split;

    la_phase1<<<NH * split, 256, 0, stream>>>(K, V, partials, split, schunk);

    const int red_blocks = (NH * KVSZ + 255) / 256;   // 1105 exactly
    la_reduce<<<red_blocks, 256, 0, stream>>>(partials, kvt, split);

    la_phase2<<<NH * (L_L / 128), 256, 0, stream>>>(Q, kvt, out);
}